// Round 2
// baseline (349.870 us; speedup 1.0000x reference)
//
#include <hip/hip_runtime.h>
#include <hip/hip_bf16.h>

#define BWIN 256
#define NTOK 343
#define CDIM 192
#define NH   6
#define HD   32
#define QKVF 576
#define NROWS (BWIN * NTOK)          // 87808
#define SCALE 0.17677669529663687f   // 1/sqrt(32)
#define LOG2E 1.4426950408889634f

typedef unsigned short u16;
typedef unsigned int   u32;
typedef short bf16x8 __attribute__((ext_vector_type(8)));
typedef float f32x4 __attribute__((ext_vector_type(4)));

// ws layout (bytes).
// qkvb has 16 logical pad rows (87808..87823) that ALIAS the start of wqb:
// attn's de-clamped K prefetch may read rows up to 87823 (finite bf16 weights,
// masked out by the -10000 j-pad bias), so no dedicated pad storage is needed.
#define OFF_QKVB 0UL                 // u16 [87808][576] = 101,154,816
#define OFF_WQB  101154816UL         // u16 [576][192]   =     221,184
#define OFF_WPB  101376000UL         // u16 [192][192]   =      73,728
#define OFF_BQS  101449728UL         // f32 [576]        =       2,304
#define OFF_BMB  101452032UL         // u16 [6][343][352]=   1,448,832
#define OFF_OPB  102900864UL         // u16 [87808][192] =  33,718,272
#define WS_NEED  136619136UL

__device__ __forceinline__ u16 f2bf(float f) {
    u32 u = __float_as_uint(f);
    u += 0x7FFFu + ((u >> 16) & 1u);           // RNE
    return (u16)(u >> 16);
}
__device__ __forceinline__ float bf2f(u16 h) {
    return __uint_as_float(((u32)h) << 16);
}
__device__ __forceinline__ u32 pk2bf(float a, float b) {
    union { __hip_bfloat162 h; u32 u; } v;
    v.h = __float22bfloat162_rn(make_float2(a, b));   // lo=a, hi=b
    return v.u;
}

__global__ void ws_too_small_sentinel(float* out) { out[0] = 1.0e6f; }

// ---------------------------------------------------------------- small converts
__global__ __launch_bounds__(256) void cvt_small(
    const float* __restrict__ wq, const float* __restrict__ wp,
    const float* __restrict__ bq, const float* __restrict__ btab,
    const int* __restrict__ ridx,
    u16* __restrict__ wqb, u16* __restrict__ wpb,
    float* __restrict__ bqs, u16* __restrict__ bmb)
{
    const int i = blockIdx.x * 256 + threadIdx.x;
    if (i < 110592) {                                 // w_qkv; q rows scaled
        const int f = i / 192;
        wqb[i] = f2bf(wq[i] * (f < CDIM ? SCALE * LOG2E : 1.0f));
    } else if (i < 147456) {
        wpb[i - 110592] = f2bf(wp[i - 110592]);
    } else if (i < 148032) {
        const int f = i - 147456;
        bqs[f] = bq[f] * (f < CDIM ? SCALE * LOG2E : 1.0f);
    } else if (i < 872448) {                          // bias bf16 [6][343][352]
        const int u = i - 148032;
        const int hh = u / 120736;                    // 343*352
        const int rem = u - hh * 120736;
        const int q = rem / 352;
        const int j = rem - q * 352;
        const float v = (j < NTOK) ? btab[ridx[q * NTOK + j] * NH + hh] * LOG2E
                                   : -10000.0f;
        bmb[(hh * NTOK + q) * 352 + j] = f2bf(v);
    }
}

// ---------------------------------------------------------------- qkv GEMM
// X tile (128 rows x full K=192) staged ONCE into LDS (f32->bf16 fused).
// W fragments read directly from global (f-chunk 37KB, L1/L2-resident).
// K-loop has ZERO barriers: ds_read_b128 + global dwordx4 + mfma only.
__global__ __launch_bounds__(256, 3) void gemm_qkv(
    const float* __restrict__ x, const u16* __restrict__ wqb,
    const float* __restrict__ bqs, u16* __restrict__ qkvb)
{
    __shared__ __align__(16) u16 smem[128 * 200];     // Xs [128][200]; epilogue Ct [128][104]
    u16* Xs = smem;
    u16* Ct = smem;
    const int f0 = blockIdx.x * 96, m0 = blockIdx.y * 128;
    const int tid = threadIdx.x;
    const int wave = tid >> 6, lane = tid & 63, g = lane >> 4, cl = lane & 15;
    const int wm = (wave >> 1) * 64, wf = (wave & 1) * 48;

    // stage X once: 128 rows x 48 float4 units = 6144 (24 passes of 256)
    #pragma unroll
    for (int p = 0; p < 24; ++p) {
        const int u = tid + 256 * p;
        const int row = u / 48, c = u - row * 48;
        const float4 v = *(const float4*)(x + (size_t)(m0 + row) * CDIM + c * 4);
        *(uint2*)(Xs + row * 200 + c * 4) = make_uint2(pk2bf(v.x, v.y), pk2bf(v.z, v.w));
    }
    __syncthreads();

    f32x4 acc[4][3];
    #pragma unroll
    for (int t = 0; t < 4; ++t)
        #pragma unroll
        for (int s = 0; s < 3; ++s) acc[t][s] = (f32x4){0.f, 0.f, 0.f, 0.f};

    const u16* wbase = wqb + (size_t)(f0 + wf + cl) * CDIM + g * 8;
    #pragma unroll
    for (int kk = 0; kk < 6; ++kk) {
        const int kcol = kk * 32;
        bf16x8 a[4], bb[3];
        #pragma unroll
        for (int s = 0; s < 3; ++s)
            bb[s] = *(const bf16x8*)(wbase + (size_t)(s * 16) * CDIM + kcol);
        #pragma unroll
        for (int t = 0; t < 4; ++t)
            a[t] = *(const bf16x8*)(Xs + (wm + t * 16 + cl) * 200 + kcol + g * 8);
        #pragma unroll
        for (int t = 0; t < 4; ++t)
            #pragma unroll
            for (int s = 0; s < 3; ++s)
                acc[t][s] = __builtin_amdgcn_mfma_f32_16x16x32_bf16(a[t], bb[s], acc[t][s], 0, 0, 0);
    }

    __syncthreads();                                  // Xs reads done; reuse as Ct
    #pragma unroll
    for (int s = 0; s < 3; ++s) {
        const float bv = bqs[f0 + wf + s * 16 + cl];
        #pragma unroll
        for (int t = 0; t < 4; ++t) {
            const int row = wm + t * 16 + g * 4;
            const int col = wf + s * 16 + cl;
            const u32 p01 = pk2bf(acc[t][s][0] + bv, acc[t][s][1] + bv);
            const u32 p23 = pk2bf(acc[t][s][2] + bv, acc[t][s][3] + bv);
            Ct[(row + 0) * 104 + col] = (u16)p01;
            Ct[(row + 1) * 104 + col] = (u16)(p01 >> 16);
            Ct[(row + 2) * 104 + col] = (u16)p23;
            Ct[(row + 3) * 104 + col] = (u16)(p23 >> 16);
        }
    }
    __syncthreads();
    #pragma unroll
    for (int p = 0; p < 6; ++p) {                     // coalesced 16B stores
        const int u = tid + 256 * p;
        const int row = u / 12, c = u - row * 12;
        *(float4*)(qkvb + (size_t)(m0 + row) * QKVF + f0 + c * 8) =
            *(const float4*)(Ct + row * 104 + c * 8);
    }
}

// ---------------------------------------------------------------- attention
// Per-jc K prefetch is de-clamped (affine): j-pad rows 87808..87823 alias wqb
// (finite values, masked by -10000 j-pad bias). Q loads / bias row bases keep
// cheap once-per-base-iteration clamps. O goes to dense opb (no false sharing).
__global__ __launch_bounds__(256, 6) void attn_mfma(
    const u16* __restrict__ qkvb, const u16* __restrict__ bmb,
    u16* __restrict__ opb)
{
    __shared__ u16 Vt[HD][352];      // [d][j-slot] 22528 B
    __shared__ u16 Os[4][16][32];    // per-wave O staging 4096 B
    const int b = blockIdx.x, h = blockIdx.y;
    const int tid = threadIdx.x;
    const int wave = tid >> 6, lane = tid & 63, g = lane >> 4, cl = lane & 15;
    const size_t rowbase = (size_t)b * NTOK;
    const u16* __restrict__ qptr = qkvb + rowbase * QKVF + h * HD;   // Q segment
    const u16* __restrict__ kptr = qptr + CDIM;                      // K segment

    for (int u = tid; u < 1408; u += 256) {           // V stage, sigma slots
        const int row = u >> 2, seg = u & 3;
        union { float4 f; u16 hx[8]; } vv;
        vv.f = make_float4(0.f, 0.f, 0.f, 0.f);
        if (row < NTOK)
            vv.f = *(const float4*)(qkvb + (rowbase + row) * QKVF + 2 * CDIM + h * HD + seg * 8);
        const int jl = row & 31;
        const int slot = (jl < 16) ? ((jl >> 2) << 3) + (jl & 3)
                                   : (((jl - 16) >> 2) << 3) + 4 + (jl & 3);
        const int pcol = (row & ~31) + slot;
        #pragma unroll
        for (int e = 0; e < 8; ++e) Vt[seg * 8 + e][pcol] = vv.hx[e];
    }
    __syncthreads();

    bf16x8 ones;
    #pragma unroll
    for (int e = 0; e < 8; ++e) ones[e] = (short)0x3F80;

    for (int base = wave * 2; base < 22; base += 8) { // 11 pairs total
        const int q0a = base * 16, q0b = q0a + 16;
        const bf16x8 qa0 = *(const bf16x8*)(qptr + (size_t)min(q0a + cl, NTOK - 1) * QKVF + g * 8);
        const bf16x8 qa1 = *(const bf16x8*)(qptr + (size_t)min(q0b + cl, NTOK - 1) * QKVF + g * 8);
        const u16* browA = bmb + ((size_t)h * NTOK + min(q0a + cl, NTOK - 1)) * 352;
        const u16* browB = bmb + ((size_t)h * NTOK + min(q0b + cl, NTOK - 1)) * 352;

        bf16x8 kb0 = *(const bf16x8*)(kptr + (size_t)cl * QKVF + g * 8);
        bf16x8 kb1 = *(const bf16x8*)(kptr + (size_t)(16 + cl) * QKVF + g * 8);
        ushort4 bA0 = *(const ushort4*)(browA + g * 4);
        ushort4 bA1 = *(const ushort4*)(browA + 16 + g * 4);
        ushort4 bB0 = *(const ushort4*)(browB + g * 4);
        ushort4 bB1 = *(const ushort4*)(browB + 16 + g * 4);

        f32x4 oA0 = {0,0,0,0}, oA1 = {0,0,0,0}, lA = {0,0,0,0};
        f32x4 oB0 = {0,0,0,0}, oB1 = {0,0,0,0}, lB = {0,0,0,0};

        for (int jc = 0; jc < 11; ++jc) {
            const int j0 = jc * 32;
            const bf16x8 ck0 = kb0, ck1 = kb1;
            const ushort4 cA0 = bA0, cA1 = bA1, cB0 = bB0, cB1 = bB1;
            if (jc < 10) {
                const int jn = j0 + 32;
                kb0 = *(const bf16x8*)(kptr + (size_t)(jn + cl) * QKVF + g * 8);
                kb1 = *(const bf16x8*)(kptr + (size_t)(jn + 16 + cl) * QKVF + g * 8);
                bA0 = *(const ushort4*)(browA + jn + g * 4);
                bA1 = *(const ushort4*)(browA + jn + 16 + g * 4);
                bB0 = *(const ushort4*)(browB + jn + g * 4);
                bB1 = *(const ushort4*)(browB + jn + 16 + g * 4);
            }
            const bf16x8 vb0 = *(const bf16x8*)&Vt[cl][j0 + g * 8];
            const bf16x8 vb1 = *(const bf16x8*)&Vt[16 + cl][j0 + g * 8];

            {
                f32x4 c0 = { bf2f(cA0.x), bf2f(cA0.y), bf2f(cA0.z), bf2f(cA0.w) };
                f32x4 c1 = { bf2f(cA1.x), bf2f(cA1.y), bf2f(cA1.z), bf2f(cA1.w) };
                const f32x4 s0 = __builtin_amdgcn_mfma_f32_16x16x32_bf16(ck0, qa0, c0, 0, 0, 0);
                const f32x4 s1 = __builtin_amdgcn_mfma_f32_16x16x32_bf16(ck1, qa0, c1, 0, 0, 0);
                union { bf16x8 v; u32 w[4]; } pa;
                pa.w[0] = pk2bf(__builtin_amdgcn_exp2f(s0[0]), __builtin_amdgcn_exp2f(s0[1]));
                pa.w[1] = pk2bf(__builtin_amdgcn_exp2f(s0[2]), __builtin_amdgcn_exp2f(s0[3]));
                pa.w[2] = pk2bf(__builtin_amdgcn_exp2f(s1[0]), __builtin_amdgcn_exp2f(s1[1]));
                pa.w[3] = pk2bf(__builtin_amdgcn_exp2f(s1[2]), __builtin_amdgcn_exp2f(s1[3]));
                oA0 = __builtin_amdgcn_mfma_f32_16x16x32_bf16(pa.v, vb0, oA0, 0, 0, 0);
                oA1 = __builtin_amdgcn_mfma_f32_16x16x32_bf16(pa.v, vb1, oA1, 0, 0, 0);
                lA  = __builtin_amdgcn_mfma_f32_16x16x32_bf16(pa.v, ones, lA, 0, 0, 0);
            }
            {
                f32x4 c0 = { bf2f(cB0.x), bf2f(cB0.y), bf2f(cB0.z), bf2f(cB0.w) };
                f32x4 c1 = { bf2f(cB1.x), bf2f(cB1.y), bf2f(cB1.z), bf2f(cB1.w) };
                const f32x4 s0 = __builtin_amdgcn_mfma_f32_16x16x32_bf16(ck0, qa1, c0, 0, 0, 0);
                const f32x4 s1 = __builtin_amdgcn_mfma_f32_16x16x32_bf16(ck1, qa1, c1, 0, 0, 0);
                union { bf16x8 v; u32 w[4]; } pa;
                pa.w[0] = pk2bf(__builtin_amdgcn_exp2f(s0[0]), __builtin_amdgcn_exp2f(s0[1]));
                pa.w[1] = pk2bf(__builtin_amdgcn_exp2f(s0[2]), __builtin_amdgcn_exp2f(s0[3]));
                pa.w[2] = pk2bf(__builtin_amdgcn_exp2f(s1[0]), __builtin_amdgcn_exp2f(s1[1]));
                pa.w[3] = pk2bf(__builtin_amdgcn_exp2f(s1[2]), __builtin_amdgcn_exp2f(s1[3]));
                oB0 = __builtin_amdgcn_mfma_f32_16x16x32_bf16(pa.v, vb0, oB0, 0, 0, 0);
                oB1 = __builtin_amdgcn_mfma_f32_16x16x32_bf16(pa.v, vb1, oB1, 0, 0, 0);
                lB  = __builtin_amdgcn_mfma_f32_16x16x32_bf16(pa.v, ones, lB, 0, 0, 0);
            }
        }
        #pragma unroll
        for (int half = 0; half < 2; ++half) {
            const f32x4 o0 = half ? oB0 : oA0;
            const f32x4 o1 = half ? oB1 : oA1;
            const f32x4 lc = half ? lB : lA;
            const int q0 = half ? q0b : q0a;
            #pragma unroll
            for (int r = 0; r < 4; ++r) {
                const float inv = 1.0f / lc[r];
                Os[wave][g * 4 + r][cl]      = f2bf(o0[r] * inv);
                Os[wave][g * 4 + r][16 + cl] = f2bf(o1[r] * inv);
            }
            const int row = lane >> 2, cg = (lane & 3) * 8;
            const int q = q0 + row;
            if (q < NTOK)
                *(float4*)(opb + (rowbase + q) * CDIM + h * HD + cg) =
                    *(const float4*)&Os[wave][row][cg];
        }
    }
}

// ---------------------------------------------------------------- proj GEMM
// Single-stage: opb tile staged once, W frags from global, barrier-free
// K-loop, f32 out via 2-pass LDS-transpose epilogue.
__global__ __launch_bounds__(256, 3) void gemm_proj(
    const u16* __restrict__ opb, const u16* __restrict__ wpb,
    const float* __restrict__ bp, float* __restrict__ out)
{
    __shared__ __align__(16) u16 smem[128 * 200];
    u16*   Xs = smem;
    float* Cf = (float*)smem;                         // [64][104] f32
    const int f0 = blockIdx.x * 96, m0 = blockIdx.y * 128;
    const int tid = threadIdx.x;
    const int wave = tid >> 6, lane = tid & 63, g = lane >> 4, cl = lane & 15;
    const int wm = (wave >> 1) * 64, wf = (wave & 1) * 48;

    // stage once: 128 rows x 24 float4 units = 3072
    #pragma unroll
    for (int p = 0; p < 12; ++p) {
        const int u = tid + 256 * p;
        const int row = u / 24, c = u - row * 24;
        *(float4*)(Xs + row * 200 + c * 8) =
            *(const float4*)(opb + (size_t)(m0 + row) * CDIM + c * 8);
    }
    __syncthreads();

    f32x4 acc[4][3];
    #pragma unroll
    for (int t = 0; t < 4; ++t)
        #pragma unroll
        for (int s = 0; s < 3; ++s) acc[t][s] = (f32x4){0.f, 0.f, 0.f, 0.f};

    const u16* wbase = wpb + (size_t)(f0 + wf + cl) * CDIM + g * 8;
    #pragma unroll
    for (int kk = 0; kk < 6; ++kk) {
        const int kcol = kk * 32;
        bf16x8 a[4], bb[3];
        #pragma unroll
        for (int s = 0; s < 3; ++s)
            bb[s] = *(const bf16x8*)(wbase + (size_t)(s * 16) * CDIM + kcol);
        #pragma unroll
        for (int t = 0; t < 4; ++t)
            a[t] = *(const bf16x8*)(Xs + (wm + t * 16 + cl) * 200 + kcol + g * 8);
        #pragma unroll
        for (int t = 0; t < 4; ++t)
            #pragma unroll
            for (int s = 0; s < 3; ++s)
                acc[t][s] = __builtin_amdgcn_mfma_f32_16x16x32_bf16(a[t], bb[s], acc[t][s], 0, 0, 0);
    }

    #pragma unroll
    for (int half = 0; half < 2; ++half) {
        __syncthreads();
        if ((wave >> 1) == half) {
            #pragma unroll
            for (int s = 0; s < 3; ++s) {
                const float bv = bp[f0 + wf + s * 16 + cl];
                #pragma unroll
                for (int t = 0; t < 4; ++t)
                    #pragma unroll
                    for (int r = 0; r < 4; ++r)
                        Cf[(t * 16 + g * 4 + r) * 104 + wf + s * 16 + cl] = acc[t][s][r] + bv;
            }
        }
        __syncthreads();
        #pragma unroll
        for (int p = 0; p < 6; ++p) {
            const int u = tid + 256 * p;
            const int row = u / 24, c = u - row * 24;
            *(float4*)(out + (size_t)(m0 + half * 64 + row) * CDIM + f0 + c * 4) =
                *(const float4*)(Cf + row * 104 + c * 4);
        }
    }
}

// ---------------------------------------------------------------- launch
extern "C" void kernel_launch(void* const* d_in, const int* in_sizes, int n_in,
                              void* d_out, int out_size, void* d_ws, size_t ws_size,
                              hipStream_t stream) {
    const float* x     = (const float*)d_in[0];
    const float* wqkv  = (const float*)d_in[1];
    const float* bqkv  = (const float*)d_in[2];
    const float* wproj = (const float*)d_in[3];
    const float* bproj = (const float*)d_in[4];
    const float* btab  = (const float*)d_in[5];
    const int*   ridx  = (const int*)d_in[6];
    float* out = (float*)d_out;

    if (ws_size < WS_NEED) {
        hipLaunchKernelGGL(ws_too_small_sentinel, dim3(1), dim3(1), 0, stream, out);
        return;
    }
    char* ws = (char*)d_ws;
    u16*   qkvb = (u16*)(ws + OFF_QKVB);
    u16*   wqb  = (u16*)(ws + OFF_WQB);
    u16*   wpb  = (u16*)(ws + OFF_WPB);
    float* bqs  = (float*)(ws + OFF_BQS);
    u16*   bmb  = (u16*)(ws + OFF_BMB);
    u16*   opb  = (u16*)(ws + OFF_OPB);

    hipLaunchKernelGGL(cvt_small, dim3(3408), dim3(256), 0, stream,
                       wqkv, wproj, bqkv, btab, ridx, wqb, wpb, bqs, bmb);
    hipLaunchKernelGGL(gemm_qkv, dim3(6, NROWS / 128), dim3(256), 0, stream,
                       x, wqb, bqs, qkvb);
    hipLaunchKernelGGL(attn_mfma, dim3(BWIN, NH), dim3(256), 0, stream,
                       qkvb, bmb, opb);
    hipLaunchKernelGGL(gemm_proj, dim3(2, NROWS / 128), dim3(256), 0, stream,
                       opb, wpb, bproj, out);
}

// Round 3
// 323.653 us; speedup vs baseline: 1.0810x; 1.0810x over previous
//
#include <hip/hip_runtime.h>
#include <hip/hip_bf16.h>

#define BWIN 256
#define NTOK 343
#define CDIM 192
#define NH   6
#define HD   32
#define QKVF 576
#define NROWS (BWIN * NTOK)          // 87808
#define SCALE 0.17677669529663687f   // 1/sqrt(32)
#define LOG2E 1.4426950408889634f

typedef unsigned short u16;
typedef unsigned int   u32;
typedef short bf16x8 __attribute__((ext_vector_type(8)));
typedef float f32x4 __attribute__((ext_vector_type(4)));

// ws layout (bytes).
// qkvb has 16 logical pad rows (87808..87823) that ALIAS the start of wqb:
// attn's de-clamped K prefetch may read rows up to 87823 (finite bf16 weights,
// masked out by the -10000 j-pad bias), so no dedicated pad storage is needed.
#define OFF_QKVB 0UL                 // u16 [87808][576] = 101,154,816
#define OFF_WQB  101154816UL         // u16 [576][192]   =     221,184
#define OFF_WPB  101376000UL         // u16 [192][192]   =      73,728
#define OFF_BQS  101449728UL         // f32 [576]        =       2,304
#define OFF_BMB  101452032UL         // u16 [6][343][352]=   1,448,832
#define OFF_OPB  102900864UL         // u16 [87808][192] =  33,718,272
#define WS_NEED  136619136UL

__device__ __forceinline__ u16 f2bf(float f) {
    u32 u = __float_as_uint(f);
    u += 0x7FFFu + ((u >> 16) & 1u);           // RNE
    return (u16)(u >> 16);
}
__device__ __forceinline__ float bf2f(u16 h) {
    return __uint_as_float(((u32)h) << 16);
}
__device__ __forceinline__ u32 pk2bf(float a, float b) {
    union { __hip_bfloat162 h; u32 u; } v;
    v.h = __float22bfloat162_rn(make_float2(a, b));   // lo=a, hi=b
    return v.u;
}

__global__ void ws_too_small_sentinel(float* out) { out[0] = 1.0e6f; }

// ---------------------------------------------------------------- small converts
__global__ __launch_bounds__(256) void cvt_small(
    const float* __restrict__ wq, const float* __restrict__ wp,
    const float* __restrict__ bq, const float* __restrict__ btab,
    const int* __restrict__ ridx,
    u16* __restrict__ wqb, u16* __restrict__ wpb,
    float* __restrict__ bqs, u16* __restrict__ bmb)
{
    const int i = blockIdx.x * 256 + threadIdx.x;
    if (i < 110592) {                                 // w_qkv; q rows scaled
        const int f = i / 192;
        wqb[i] = f2bf(wq[i] * (f < CDIM ? SCALE * LOG2E : 1.0f));
    } else if (i < 147456) {
        wpb[i - 110592] = f2bf(wp[i - 110592]);
    } else if (i < 148032) {
        const int f = i - 147456;
        bqs[f] = bq[f] * (f < CDIM ? SCALE * LOG2E : 1.0f);
    } else if (i < 872448) {                          // bias bf16 [6][343][352]
        const int u = i - 148032;
        const int hh = u / 120736;                    // 343*352
        const int rem = u - hh * 120736;
        const int q = rem / 352;
        const int j = rem - q * 352;
        const float v = (j < NTOK) ? btab[ridx[q * NTOK + j] * NH + hh] * LOG2E
                                   : -10000.0f;
        bmb[(hh * NTOK + q) * 352 + j] = f2bf(v);
    }
}

// ---------------------------------------------------------------- qkv GEMM
// X tile (128 rows x full K=192) staged ONCE into LDS (f32->bf16 fused).
// W fragments read directly from global (f-chunk 37KB, L1/L2-resident).
// K-loop has ZERO barriers: ds_read_b128 + global dwordx4 + mfma only.
__global__ __launch_bounds__(256, 3) void gemm_qkv(
    const float* __restrict__ x, const u16* __restrict__ wqb,
    const float* __restrict__ bqs, u16* __restrict__ qkvb)
{
    __shared__ __align__(16) u16 smem[128 * 200];     // Xs [128][200]; epilogue Ct [128][104]
    u16* Xs = smem;
    u16* Ct = smem;
    const int f0 = blockIdx.x * 96, m0 = blockIdx.y * 128;
    const int tid = threadIdx.x;
    const int wave = tid >> 6, lane = tid & 63, g = lane >> 4, cl = lane & 15;
    const int wm = (wave >> 1) * 64, wf = (wave & 1) * 48;

    // stage X once: 128 rows x 48 float4 units = 6144 (24 passes of 256)
    #pragma unroll
    for (int p = 0; p < 24; ++p) {
        const int u = tid + 256 * p;
        const int row = u / 48, c = u - row * 48;
        const float4 v = *(const float4*)(x + (size_t)(m0 + row) * CDIM + c * 4);
        *(uint2*)(Xs + row * 200 + c * 4) = make_uint2(pk2bf(v.x, v.y), pk2bf(v.z, v.w));
    }
    __syncthreads();

    f32x4 acc[4][3];
    #pragma unroll
    for (int t = 0; t < 4; ++t)
        #pragma unroll
        for (int s = 0; s < 3; ++s) acc[t][s] = (f32x4){0.f, 0.f, 0.f, 0.f};

    const u16* wbase = wqb + (size_t)(f0 + wf + cl) * CDIM + g * 8;
    #pragma unroll
    for (int kk = 0; kk < 6; ++kk) {
        const int kcol = kk * 32;
        bf16x8 a[4], bb[3];
        #pragma unroll
        for (int s = 0; s < 3; ++s)
            bb[s] = *(const bf16x8*)(wbase + (size_t)(s * 16) * CDIM + kcol);
        #pragma unroll
        for (int t = 0; t < 4; ++t)
            a[t] = *(const bf16x8*)(Xs + (wm + t * 16 + cl) * 200 + kcol + g * 8);
        #pragma unroll
        for (int t = 0; t < 4; ++t)
            #pragma unroll
            for (int s = 0; s < 3; ++s)
                acc[t][s] = __builtin_amdgcn_mfma_f32_16x16x32_bf16(a[t], bb[s], acc[t][s], 0, 0, 0);
    }

    __syncthreads();                                  // Xs reads done; reuse as Ct
    #pragma unroll
    for (int s = 0; s < 3; ++s) {
        const float bv = bqs[f0 + wf + s * 16 + cl];
        #pragma unroll
        for (int t = 0; t < 4; ++t) {
            const int row = wm + t * 16 + g * 4;
            const int col = wf + s * 16 + cl;
            const u32 p01 = pk2bf(acc[t][s][0] + bv, acc[t][s][1] + bv);
            const u32 p23 = pk2bf(acc[t][s][2] + bv, acc[t][s][3] + bv);
            Ct[(row + 0) * 104 + col] = (u16)p01;
            Ct[(row + 1) * 104 + col] = (u16)(p01 >> 16);
            Ct[(row + 2) * 104 + col] = (u16)p23;
            Ct[(row + 3) * 104 + col] = (u16)(p23 >> 16);
        }
    }
    __syncthreads();
    #pragma unroll
    for (int p = 0; p < 6; ++p) {                     // coalesced 16B stores
        const int u = tid + 256 * p;
        const int row = u / 12, c = u - row * 12;
        *(float4*)(qkvb + (size_t)(m0 + row) * QKVF + f0 + c * 8) =
            *(const float4*)(Ct + row * 104 + c * 8);
    }
}

// ---------------------------------------------------------------- attention
// De-clamped per-jc K prefetch (affine; pad rows alias wqb, masked by j-pad
// bias). Q/bias row clamps are outside the jc loop (cheap). Dense opb output.
// Occupancy pinned at 4 blocks/CU: at 6, co-resident working set overflows the
// 4 MiB/XCD L2 -> K re-fetch (3x/block) + partial-line opb writeback doubling
// (measured R2: FETCH 84->179 MB, WRITE 39->90 MB).
__global__ __launch_bounds__(256, 4) void attn_mfma(
    const u16* __restrict__ qkvb, const u16* __restrict__ bmb,
    u16* __restrict__ opb)
{
    __shared__ u16 Vt[HD][352];      // [d][j-slot] 22528 B
    __shared__ u16 Os[4][16][32];    // per-wave O staging 4096 B
    const int b = blockIdx.x, h = blockIdx.y;
    const int tid = threadIdx.x;
    const int wave = tid >> 6, lane = tid & 63, g = lane >> 4, cl = lane & 15;
    const size_t rowbase = (size_t)b * NTOK;
    const u16* __restrict__ qptr = qkvb + rowbase * QKVF + h * HD;   // Q segment
    const u16* __restrict__ kptr = qptr + CDIM;                      // K segment

    for (int u = tid; u < 1408; u += 256) {           // V stage, sigma slots
        const int row = u >> 2, seg = u & 3;
        union { float4 f; u16 hx[8]; } vv;
        vv.f = make_float4(0.f, 0.f, 0.f, 0.f);
        if (row < NTOK)
            vv.f = *(const float4*)(qkvb + (rowbase + row) * QKVF + 2 * CDIM + h * HD + seg * 8);
        const int jl = row & 31;
        const int slot = (jl < 16) ? ((jl >> 2) << 3) + (jl & 3)
                                   : (((jl - 16) >> 2) << 3) + 4 + (jl & 3);
        const int pcol = (row & ~31) + slot;
        #pragma unroll
        for (int e = 0; e < 8; ++e) Vt[seg * 8 + e][pcol] = vv.hx[e];
    }
    __syncthreads();

    bf16x8 ones;
    #pragma unroll
    for (int e = 0; e < 8; ++e) ones[e] = (short)0x3F80;

    for (int base = wave * 2; base < 22; base += 8) { // 11 pairs total
        const int q0a = base * 16, q0b = q0a + 16;
        const bf16x8 qa0 = *(const bf16x8*)(qptr + (size_t)min(q0a + cl, NTOK - 1) * QKVF + g * 8);
        const bf16x8 qa1 = *(const bf16x8*)(qptr + (size_t)min(q0b + cl, NTOK - 1) * QKVF + g * 8);
        const u16* browA = bmb + ((size_t)h * NTOK + min(q0a + cl, NTOK - 1)) * 352;
        const u16* browB = bmb + ((size_t)h * NTOK + min(q0b + cl, NTOK - 1)) * 352;

        bf16x8 kb0 = *(const bf16x8*)(kptr + (size_t)cl * QKVF + g * 8);
        bf16x8 kb1 = *(const bf16x8*)(kptr + (size_t)(16 + cl) * QKVF + g * 8);
        ushort4 bA0 = *(const ushort4*)(browA + g * 4);
        ushort4 bA1 = *(const ushort4*)(browA + 16 + g * 4);
        ushort4 bB0 = *(const ushort4*)(browB + g * 4);
        ushort4 bB1 = *(const ushort4*)(browB + 16 + g * 4);

        f32x4 oA0 = {0,0,0,0}, oA1 = {0,0,0,0}, lA = {0,0,0,0};
        f32x4 oB0 = {0,0,0,0}, oB1 = {0,0,0,0}, lB = {0,0,0,0};

        for (int jc = 0; jc < 11; ++jc) {
            const int j0 = jc * 32;
            const bf16x8 ck0 = kb0, ck1 = kb1;
            const ushort4 cA0 = bA0, cA1 = bA1, cB0 = bB0, cB1 = bB1;
            if (jc < 10) {
                const int jn = j0 + 32;
                kb0 = *(const bf16x8*)(kptr + (size_t)(jn + cl) * QKVF + g * 8);
                kb1 = *(const bf16x8*)(kptr + (size_t)(jn + 16 + cl) * QKVF + g * 8);
                bA0 = *(const ushort4*)(browA + jn + g * 4);
                bA1 = *(const ushort4*)(browA + jn + 16 + g * 4);
                bB0 = *(const ushort4*)(browB + jn + g * 4);
                bB1 = *(const ushort4*)(browB + jn + 16 + g * 4);
            }
            const bf16x8 vb0 = *(const bf16x8*)&Vt[cl][j0 + g * 8];
            const bf16x8 vb1 = *(const bf16x8*)&Vt[16 + cl][j0 + g * 8];

            {
                f32x4 c0 = { bf2f(cA0.x), bf2f(cA0.y), bf2f(cA0.z), bf2f(cA0.w) };
                f32x4 c1 = { bf2f(cA1.x), bf2f(cA1.y), bf2f(cA1.z), bf2f(cA1.w) };
                const f32x4 s0 = __builtin_amdgcn_mfma_f32_16x16x32_bf16(ck0, qa0, c0, 0, 0, 0);
                const f32x4 s1 = __builtin_amdgcn_mfma_f32_16x16x32_bf16(ck1, qa0, c1, 0, 0, 0);
                union { bf16x8 v; u32 w[4]; } pa;
                pa.w[0] = pk2bf(__builtin_amdgcn_exp2f(s0[0]), __builtin_amdgcn_exp2f(s0[1]));
                pa.w[1] = pk2bf(__builtin_amdgcn_exp2f(s0[2]), __builtin_amdgcn_exp2f(s0[3]));
                pa.w[2] = pk2bf(__builtin_amdgcn_exp2f(s1[0]), __builtin_amdgcn_exp2f(s1[1]));
                pa.w[3] = pk2bf(__builtin_amdgcn_exp2f(s1[2]), __builtin_amdgcn_exp2f(s1[3]));
                oA0 = __builtin_amdgcn_mfma_f32_16x16x32_bf16(pa.v, vb0, oA0, 0, 0, 0);
                oA1 = __builtin_amdgcn_mfma_f32_16x16x32_bf16(pa.v, vb1, oA1, 0, 0, 0);
                lA  = __builtin_amdgcn_mfma_f32_16x16x32_bf16(pa.v, ones, lA, 0, 0, 0);
            }
            {
                f32x4 c0 = { bf2f(cB0.x), bf2f(cB0.y), bf2f(cB0.z), bf2f(cB0.w) };
                f32x4 c1 = { bf2f(cB1.x), bf2f(cB1.y), bf2f(cB1.z), bf2f(cB1.w) };
                const f32x4 s0 = __builtin_amdgcn_mfma_f32_16x16x32_bf16(ck0, qa1, c0, 0, 0, 0);
                const f32x4 s1 = __builtin_amdgcn_mfma_f32_16x16x32_bf16(ck1, qa1, c1, 0, 0, 0);
                union { bf16x8 v; u32 w[4]; } pa;
                pa.w[0] = pk2bf(__builtin_amdgcn_exp2f(s0[0]), __builtin_amdgcn_exp2f(s0[1]));
                pa.w[1] = pk2bf(__builtin_amdgcn_exp2f(s0[2]), __builtin_amdgcn_exp2f(s0[3]));
                pa.w[2] = pk2bf(__builtin_amdgcn_exp2f(s1[0]), __builtin_amdgcn_exp2f(s1[1]));
                pa.w[3] = pk2bf(__builtin_amdgcn_exp2f(s1[2]), __builtin_amdgcn_exp2f(s1[3]));
                oB0 = __builtin_amdgcn_mfma_f32_16x16x32_bf16(pa.v, vb0, oB0, 0, 0, 0);
                oB1 = __builtin_amdgcn_mfma_f32_16x16x32_bf16(pa.v, vb1, oB1, 0, 0, 0);
                lB  = __builtin_amdgcn_mfma_f32_16x16x32_bf16(pa.v, ones, lB, 0, 0, 0);
            }
        }
        #pragma unroll
        for (int half = 0; half < 2; ++half) {
            const f32x4 o0 = half ? oB0 : oA0;
            const f32x4 o1 = half ? oB1 : oA1;
            const f32x4 lc = half ? lB : lA;
            const int q0 = half ? q0b : q0a;
            #pragma unroll
            for (int r = 0; r < 4; ++r) {
                const float inv = 1.0f / lc[r];
                Os[wave][g * 4 + r][cl]      = f2bf(o0[r] * inv);
                Os[wave][g * 4 + r][16 + cl] = f2bf(o1[r] * inv);
            }
            const int row = lane >> 2, cg = (lane & 3) * 8;
            const int q = q0 + row;
            if (q < NTOK)
                *(float4*)(opb + (rowbase + q) * CDIM + h * HD + cg) =
                    *(const float4*)&Os[wave][row][cg];
        }
    }
}

// ---------------------------------------------------------------- proj GEMM
// Single-stage: opb tile staged once, W frags from global, barrier-free
// K-loop, f32 out via 2-pass LDS-transpose epilogue.
__global__ __launch_bounds__(256, 3) void gemm_proj(
    const u16* __restrict__ opb, const u16* __restrict__ wpb,
    const float* __restrict__ bp, float* __restrict__ out)
{
    __shared__ __align__(16) u16 smem[128 * 200];
    u16*   Xs = smem;
    float* Cf = (float*)smem;                         // [64][104] f32
    const int f0 = blockIdx.x * 96, m0 = blockIdx.y * 128;
    const int tid = threadIdx.x;
    const int wave = tid >> 6, lane = tid & 63, g = lane >> 4, cl = lane & 15;
    const int wm = (wave >> 1) * 64, wf = (wave & 1) * 48;

    // stage once: 128 rows x 24 float4 units = 3072
    #pragma unroll
    for (int p = 0; p < 12; ++p) {
        const int u = tid + 256 * p;
        const int row = u / 24, c = u - row * 24;
        *(float4*)(Xs + row * 200 + c * 8) =
            *(const float4*)(opb + (size_t)(m0 + row) * CDIM + c * 8);
    }
    __syncthreads();

    f32x4 acc[4][3];
    #pragma unroll
    for (int t = 0; t < 4; ++t)
        #pragma unroll
        for (int s = 0; s < 3; ++s) acc[t][s] = (f32x4){0.f, 0.f, 0.f, 0.f};

    const u16* wbase = wpb + (size_t)(f0 + wf + cl) * CDIM + g * 8;
    #pragma unroll
    for (int kk = 0; kk < 6; ++kk) {
        const int kcol = kk * 32;
        bf16x8 a[4], bb[3];
        #pragma unroll
        for (int s = 0; s < 3; ++s)
            bb[s] = *(const bf16x8*)(wbase + (size_t)(s * 16) * CDIM + kcol);
        #pragma unroll
        for (int t = 0; t < 4; ++t)
            a[t] = *(const bf16x8*)(Xs + (wm + t * 16 + cl) * 200 + kcol + g * 8);
        #pragma unroll
        for (int t = 0; t < 4; ++t)
            #pragma unroll
            for (int s = 0; s < 3; ++s)
                acc[t][s] = __builtin_amdgcn_mfma_f32_16x16x32_bf16(a[t], bb[s], acc[t][s], 0, 0, 0);
    }

    #pragma unroll
    for (int half = 0; half < 2; ++half) {
        __syncthreads();
        if ((wave >> 1) == half) {
            #pragma unroll
            for (int s = 0; s < 3; ++s) {
                const float bv = bp[f0 + wf + s * 16 + cl];
                #pragma unroll
                for (int t = 0; t < 4; ++t)
                    #pragma unroll
                    for (int r = 0; r < 4; ++r)
                        Cf[(t * 16 + g * 4 + r) * 104 + wf + s * 16 + cl] = acc[t][s][r] + bv;
            }
        }
        __syncthreads();
        #pragma unroll
        for (int p = 0; p < 6; ++p) {
            const int u = tid + 256 * p;
            const int row = u / 24, c = u - row * 24;
            *(float4*)(out + (size_t)(m0 + half * 64 + row) * CDIM + f0 + c * 4) =
                *(const float4*)(Cf + row * 104 + c * 4);
        }
    }
}

// ---------------------------------------------------------------- launch
extern "C" void kernel_launch(void* const* d_in, const int* in_sizes, int n_in,
                              void* d_out, int out_size, void* d_ws, size_t ws_size,
                              hipStream_t stream) {
    const float* x     = (const float*)d_in[0];
    const float* wqkv  = (const float*)d_in[1];
    const float* bqkv  = (const float*)d_in[2];
    const float* wproj = (const float*)d_in[3];
    const float* bproj = (const float*)d_in[4];
    const float* btab  = (const float*)d_in[5];
    const int*   ridx  = (const int*)d_in[6];
    float* out = (float*)d_out;

    if (ws_size < WS_NEED) {
        hipLaunchKernelGGL(ws_too_small_sentinel, dim3(1), dim3(1), 0, stream, out);
        return;
    }
    char* ws = (char*)d_ws;
    u16*   qkvb = (u16*)(ws + OFF_QKVB);
    u16*   wqb  = (u16*)(ws + OFF_WQB);
    u16*   wpb  = (u16*)(ws + OFF_WPB);
    float* bqs  = (float*)(ws + OFF_BQS);
    u16*   bmb  = (u16*)(ws + OFF_BMB);
    u16*   opb  = (u16*)(ws + OFF_OPB);

    hipLaunchKernelGGL(cvt_small, dim3(3408), dim3(256), 0, stream,
                       wqkv, wproj, bqkv, btab, ridx, wqb, wpb, bqs, bmb);
    hipLaunchKernelGGL(gemm_qkv, dim3(6, NROWS / 128), dim3(256), 0, stream,
                       x, wqb, bqs, qkvb);
    hipLaunchKernelGGL(attn_mfma, dim3(BWIN, NH), dim3(256), 0, stream,
                       qkvb, bmb, opb);
    hipLaunchKernelGGL(gemm_proj, dim3(2, NROWS / 128), dim3(256), 0, stream,
                       opb, wpb, bproj, out);
}